// Round 3
// baseline (201.476 us; speedup 1.0000x reference)
//
#include <hip/hip_runtime.h>
#include <hip/hip_bf16.h>
#include <stdint.h>

// CausalDerivative: out[b,i] = sum_h W2[i,h] * relu(sum_n x[b,n]*W1[i,h,n]*M[i,n])
//   x[b,n] = (n<16) ? (inputs[b,n]>0 ? 1 : 0) : inputs[b,n]   (straight-through fwd)
//   M = ones, except row 63 keeps only n==63 (HIDDEN_FLAG one-hot-last)
// B=32768, N=64, H=64.
//
// Defensive layer:
//  - input pointers resolved by in_sizes (robust to the t scalar being dropped)
//  - device-side dtype sniff (bf16 vs fp32) on `inputs`, wave-uniform branch

typedef __attribute__((ext_vector_type(8))) short short8;   // 8 bf16 = 4 VGPRs
typedef __attribute__((ext_vector_type(4))) float floatx4;  // MFMA acc

#define NN 64
#define HH 64
#define BB 32768

__device__ __forceinline__ unsigned short f32_to_bf16_bits(float f) {
    union { float f; unsigned int i; } c; c.f = f;
    unsigned int b = c.i;
    b += 0x7fffu + ((b >> 16) & 1u);   // RNE
    return (unsigned short)(b >> 16);
}

template<bool F32>
__device__ __forceinline__ void run_body(const void* xp, const void* w1p,
                                         const void* w2p, void* outp)
{
    const int tid  = threadIdx.x;
    const int wave = tid >> 6;
    const int lane = tid & 63;
    const int quad = lane >> 4;   // 0..3
    const int l16  = lane & 15;   // 0..15

    // grid: blk = ng*512 + rb -> 16 node-groups x 512 row-blocks.
    const int blk  = blockIdx.x;
    const int ng   = blk >> 9;        // 0..15
    const int rb   = blk & 511;       // 0..511
    const int node = ng * 4 + wave;   // 0..63
    const int b0   = rb * 64;         // batch row base

    // ---- B fragments: B[k][h] = W1[node][h][k];  h = ht*16+l16, k = ks*32+quad*8+j
    short8 bfrag[2][4];
    #pragma unroll
    for (int ks = 0; ks < 2; ++ks) {
        #pragma unroll
        for (int ht = 0; ht < 4; ++ht) {
            const int h = ht * 16 + l16;
            const int k = ks * 32 + quad * 8;
            short8 v;
            if (F32) {
                const float* p = (const float*)w1p + node * (HH * NN) + h * NN + k;
                float4 a0 = *(const float4*)(p);
                float4 a1 = *(const float4*)(p + 4);
                float vals[8] = {a0.x, a0.y, a0.z, a0.w, a1.x, a1.y, a1.z, a1.w};
                #pragma unroll
                for (int j = 0; j < 8; ++j) v[j] = (short)f32_to_bf16_bits(vals[j]);
            } else {
                const ushort* p = (const ushort*)w1p + node * (HH * NN) + h * NN + k;
                v = *(const short8*)p;
            }
            if (node == 63) {                 // hidden node: only input n==63 survives
                #pragma unroll
                for (int j = 0; j < 8; ++j)
                    if (k + j != 63) v[j] = 0;
            }
            bfrag[ks][ht] = v;
        }
    }

    // ---- A fragments: A[m][k] = x[b0+m][k];  m = rt*16+l16, k = ks*32+quad*8+j
    short8 afrag[2][4];
    #pragma unroll
    for (int ks = 0; ks < 2; ++ks) {
        #pragma unroll
        for (int rt = 0; rt < 4; ++rt) {
            const int row = b0 + rt * 16 + l16;
            const int k   = ks * 32 + quad * 8;
            const bool gate = (ks == 0 && quad < 2);   // k in [0,16): straight-through
            short8 v;
            if (F32) {
                const float* p = (const float*)xp + row * NN + k;
                float4 a0 = *(const float4*)(p);
                float4 a1 = *(const float4*)(p + 4);
                float vals[8] = {a0.x, a0.y, a0.z, a0.w, a1.x, a1.y, a1.z, a1.w};
                #pragma unroll
                for (int j = 0; j < 8; ++j) {
                    if (gate) v[j] = (vals[j] > 0.f) ? (short)0x3F80 : (short)0;
                    else      v[j] = (short)f32_to_bf16_bits(vals[j]);
                }
            } else {
                const ushort* p = (const ushort*)xp + row * NN + k;
                v = *(const short8*)p;
                if (gate) {
                    #pragma unroll
                    for (int j = 0; j < 8; ++j) {
                        const unsigned short u = (unsigned short)v[j];
                        const bool pos = ((u & 0x8000u) == 0) && ((u & 0x7fffu) != 0);
                        v[j] = pos ? (short)0x3F80 : (short)0;   // bf16 1.0 : 0.0
                    }
                }
            }
            afrag[ks][rt] = v;
        }
    }

    // ---- MFMA: Hidden tile [64 rows x 64 h] for this node
    floatx4 acc[4][4];
    #pragma unroll
    for (int rt = 0; rt < 4; ++rt)
        #pragma unroll
        for (int ht = 0; ht < 4; ++ht)
            acc[rt][ht] = (floatx4){0.f, 0.f, 0.f, 0.f};

    #pragma unroll
    for (int ks = 0; ks < 2; ++ks)
        #pragma unroll
        for (int rt = 0; rt < 4; ++rt)
            #pragma unroll
            for (int ht = 0; ht < 4; ++ht)
                acc[rt][ht] = __builtin_amdgcn_mfma_f32_16x16x32_bf16(
                    afrag[ks][rt], bfrag[ks][ht], acc[rt][ht], 0, 0, 0);

    // ---- epilogue: out[b, node] = sum_h relu(Hidden[b,h]) * W2[node,h]
    float w2reg[4];
    #pragma unroll
    for (int ht = 0; ht < 4; ++ht) {
        const int idx = node * HH + ht * 16 + l16;
        if (F32) {
            w2reg[ht] = ((const float*)w2p)[idx];
        } else {
            const ushort u = ((const ushort*)w2p)[idx];
            union { unsigned int i; float f; } cv; cv.i = ((unsigned int)u) << 16;
            w2reg[ht] = cv.f;
        }
    }

    #pragma unroll
    for (int rt = 0; rt < 4; ++rt) {
        #pragma unroll
        for (int r = 0; r < 4; ++r) {
            float s = 0.f;
            #pragma unroll
            for (int ht = 0; ht < 4; ++ht) {
                float v = acc[rt][ht][r];     // C layout: col=l16, row=quad*4+r
                v = v > 0.f ? v : 0.f;
                s += v * w2reg[ht];
            }
            // reduce over the 16 columns (h) within each 16-lane group
            s += __shfl_xor(s, 1, 64);
            s += __shfl_xor(s, 2, 64);
            s += __shfl_xor(s, 4, 64);
            s += __shfl_xor(s, 8, 64);
            if (l16 == 0) {
                const int row = b0 + rt * 16 + quad * 4 + r;
                if (F32) {
                    ((float*)outp)[row * NN + node] = s;
                } else {
                    ((ushort*)outp)[row * NN + node] = f32_to_bf16_bits(s);
                }
            }
        }
    }
}

__global__ __launch_bounds__(256, 2)
void causal_deriv_kernel(const void* __restrict__ x,
                         const void* __restrict__ W1,
                         const void* __restrict__ W2,
                         void* __restrict__ out)
{
    // ---- dtype sniff on `inputs`: check 128 even-indexed ushorts.
    // bf16 N(0,1): exponent field in [118,132] ~99% of words.
    // fp32 low-mantissa halves: ~6%.
    const int lane = threadIdx.x & 63;
    const ushort* xw = (const ushort*)x;
    const ushort a = xw[4 * lane];
    const ushort b = xw[4 * lane + 2];
    const int ea = (a >> 7) & 0xFF, eb = (b >> 7) & 0xFF;
    const int hit = ((ea >= 118 && ea <= 132) ? 1 : 0) + ((eb >= 118 && eb <= 132) ? 1 : 0);
    const unsigned long long m1 = __ballot(hit >= 1);
    const unsigned long long m2 = __ballot(hit >= 2);
    const int hits = __popcll(m1) + __popcll(m2);
    const bool is_bf16 = (hits >= 64);

    if (is_bf16) run_body<false>(x, W1, W2, out);
    else         run_body<true >(x, W1, W2, out);
}

extern "C" void kernel_launch(void* const* d_in, const int* in_sizes, int n_in,
                              void* d_out, int out_size, void* d_ws, size_t ws_size,
                              hipStream_t stream) {
    // Resolve inputs by element count (robust to scalar t being dropped):
    //   inputs = 32768*64 = 2097152, W1 = 64*64*64 = 262144,
    //   W2 = first 4096 (adjacency is the second 4096), others unused.
    int i_in = -1, i_w1 = -1, i_w2 = -1;
    for (int i = 0; i < n_in; ++i) {
        const int s = in_sizes[i];
        if      (s == BB * NN  && i_in < 0) i_in = i;
        else if (s == NN*HH*NN && i_w1 < 0) i_w1 = i;
        else if (s == NN*HH    && i_w2 < 0) i_w2 = i;
    }
    if (i_in < 0) i_in = (n_in > 1) ? 1 : 0;
    if (i_w1 < 0) i_w1 = i_in + 1;
    if (i_w2 < 0) i_w2 = i_w1 + 1;

    causal_deriv_kernel<<<dim3(16 * 512), dim3(256), 0, stream>>>(
        d_in[i_in], d_in[i_w1], d_in[i_w2], d_out);
}

// Round 6
// 156.176 us; speedup vs baseline: 1.2901x; 1.2901x over previous
//
#include <hip/hip_runtime.h>
#include <stdint.h>

// CausalDerivative: out[b,i] = sum_h W2[i,h] * relu(sum_n x[b,n]*W1[i,h,n]*M[i,n])
//   x[b,n] = (n<16) ? (inputs[b,n]>0 ? 1 : 0) : inputs[b,n]
//   M = ones, except row 63 keeps only n==63
// B=32768, N=64, H=64.
//
// Round 6: device tensors are FP32 (round-3 passed via its F32 sniff branch;
// rounds 4-5 hardcoded bf16 -> NaN). Restore dual-path dispatch + sniff on the
// round-5 structure: wave = 64 rows x 1 node, ITER=4 chunks, loop-invariant
// B/W2 frags, per-wave LDS-transpose epilogue fenced by __syncthreads().

typedef __attribute__((ext_vector_type(8))) short short8;   // 8 bf16
typedef __attribute__((ext_vector_type(4))) float floatx4;  // MFMA acc

#define NN 64
#define HH 64
#define BB 32768
#define ITER 4
#define LDSW 20   // LDS row stride in floats (80 B: 16B-aligned rows, 2-way-benign)

__device__ __forceinline__ unsigned short f32_to_bf16_bits(float f) {
    union { float f; unsigned int i; } c; c.f = f;
    unsigned int b = c.i;
    b += 0x7fffu + ((b >> 16) & 1u);   // RNE
    return (unsigned short)(b >> 16);
}

template<bool F32>
__device__ __forceinline__ void run_body(const void* xp, const void* w1p,
                                         const void* w2p, void* outp,
                                         float* myLds)
{
    const int tid  = threadIdx.x;
    const int wave = tid >> 6;
    const int lane = tid & 63;
    const int quad = lane >> 4;   // 0..3
    const int l16  = lane & 15;   // 0..15

    // blk = ng*128 + rbg : the 16 ng-blocks sharing an x row-chunk are 128 apart
    // (== 0 mod 8) -> same XCD L2 for the shared x reads.
    const int blk  = blockIdx.x;
    const int ng   = blk >> 7;          // 0..15
    const int rbg  = blk & 127;         // 0..127
    const int node = ng * 4 + wave;     // 0..63
    const int rowbase = rbg * (ITER * 64);
    (void)wave;

    // ---- B fragments (loop-invariant): B[k][h] = W1[node][h][k]
    //      h = ht*16+l16, k = ks*32+quad*8+j
    short8 bfrag[2][4];
    #pragma unroll
    for (int ks = 0; ks < 2; ++ks) {
        #pragma unroll
        for (int ht = 0; ht < 4; ++ht) {
            const int h = ht * 16 + l16;
            const int k = ks * 32 + quad * 8;
            short8 v;
            if (F32) {
                const float* p = (const float*)w1p + node * (HH * NN) + h * NN + k;
                const float4 a0 = *(const float4*)(p);
                const float4 a1 = *(const float4*)(p + 4);
                const float vals[8] = {a0.x, a0.y, a0.z, a0.w, a1.x, a1.y, a1.z, a1.w};
                #pragma unroll
                for (int j = 0; j < 8; ++j) v[j] = (short)f32_to_bf16_bits(vals[j]);
            } else {
                v = *(const short8*)((const ushort*)w1p + node * (HH * NN) + h * NN + k);
            }
            if (node == NN - 1) {             // hidden node: only n==63 survives
                #pragma unroll
                for (int j = 0; j < 8; ++j)
                    if (k + j != NN - 1) v[j] = 0;
            }
            bfrag[ks][ht] = v;
        }
    }

    // ---- W2 (loop-invariant): lane (quad,l16) needs W2[node][ht*16+l16]
    float w2reg[4];
    #pragma unroll
    for (int ht = 0; ht < 4; ++ht) {
        const int idx = node * HH + ht * 16 + l16;
        if (F32) {
            w2reg[ht] = ((const float*)w2p)[idx];
        } else {
            const ushort u = ((const ushort*)w2p)[idx];
            union { unsigned int i; float f; } cv; cv.i = ((unsigned int)u) << 16;
            w2reg[ht] = cv.f;
        }
    }

    #pragma unroll 1
    for (int it = 0; it < ITER; ++it) {
        const int b0 = rowbase + it * 64;

        // ---- A fragments: A[m][k] = x[b0+m][k]; m = rt*16+l16, k = ks*32+quad*8+j
        short8 afrag[2][4];
        #pragma unroll
        for (int ks = 0; ks < 2; ++ks) {
            #pragma unroll
            for (int rt = 0; rt < 4; ++rt) {
                const int row = b0 + rt * 16 + l16;
                const int k   = ks * 32 + quad * 8;
                const bool gate = (ks == 0 && quad < 2);   // k in [0,16)
                short8 v;
                if (F32) {
                    const float* p = (const float*)xp + row * NN + k;
                    const float4 a0 = *(const float4*)(p);
                    const float4 a1 = *(const float4*)(p + 4);
                    const float vals[8] = {a0.x, a0.y, a0.z, a0.w, a1.x, a1.y, a1.z, a1.w};
                    #pragma unroll
                    for (int j = 0; j < 8; ++j) {
                        if (gate) v[j] = (vals[j] > 0.f) ? (short)0x3F80 : (short)0;
                        else      v[j] = (short)f32_to_bf16_bits(vals[j]);
                    }
                } else {
                    v = *(const short8*)((const ushort*)xp + row * NN + k);
                    if (gate) {
                        #pragma unroll
                        for (int j = 0; j < 8; ++j) {
                            const unsigned short u = (unsigned short)v[j];
                            const bool pos = ((u & 0x8000u) == 0) && ((u & 0x7fffu) != 0);
                            v[j] = pos ? (short)0x3F80 : (short)0;
                        }
                    }
                }
                afrag[ks][rt] = v;
            }
        }

        // ---- MFMA: Hidden tile [64 rows x 64 h]
        floatx4 acc[4][4];
        #pragma unroll
        for (int rt = 0; rt < 4; ++rt)
            #pragma unroll
            for (int ht = 0; ht < 4; ++ht)
                acc[rt][ht] = (floatx4){0.f, 0.f, 0.f, 0.f};

        #pragma unroll
        for (int ks = 0; ks < 2; ++ks)
            #pragma unroll
            for (int rt = 0; rt < 4; ++rt)
                #pragma unroll
                for (int ht = 0; ht < 4; ++ht)
                    acc[rt][ht] = __builtin_amdgcn_mfma_f32_16x16x32_bf16(
                        afrag[ks][rt], bfrag[ks][ht], acc[rt][ht], 0, 0, 0);

        // ---- epilogue: per-lane partials over its 16 h-values -> LDS transpose
        // C layout: col(h-offset)=l16, row=quad*4+r; lane holds h = ht*16+l16.
        #pragma unroll
        for (int rt = 0; rt < 4; ++rt) {
            #pragma unroll
            for (int r = 0; r < 4; ++r) {
                float s = 0.f;
                #pragma unroll
                for (int ht = 0; ht < 4; ++ht) {
                    float v = acc[rt][ht][r];
                    v = v > 0.f ? v : 0.f;
                    s = fmaf(v, w2reg[ht], s);
                }
                myLds[(rt * 16 + quad * 4 + r) * LDSW + l16] = s;
            }
        }

        __syncthreads();   // drain LDS writes (uniform across block)

        // lane = local row: read its 16 partials (contiguous, 16B-aligned), reduce
        const float* rowp = myLds + lane * LDSW;
        const float4 v0 = *(const float4*)(rowp + 0);
        const float4 v1 = *(const float4*)(rowp + 4);
        const float4 v2 = *(const float4*)(rowp + 8);
        const float4 v3 = *(const float4*)(rowp + 12);
        const float s0 = (v0.x + v0.y) + (v0.z + v0.w);
        const float s1 = (v1.x + v1.y) + (v1.z + v1.w);
        const float s2 = (v2.x + v2.y) + (v2.z + v2.w);
        const float s3 = (v3.x + v3.y) + (v3.z + v3.w);
        const float tot = (s0 + s1) + (s2 + s3);

        if (F32) ((float*) outp)[(size_t)(b0 + lane) * NN + node] = tot;
        else     ((ushort*)outp)[(size_t)(b0 + lane) * NN + node] = f32_to_bf16_bits(tot);

        __syncthreads();   // protect next iter's LDS writes vs slower waves' reads
    }
}

__global__ __launch_bounds__(256, 2)
void causal_deriv_kernel(const void* __restrict__ x,
                         const void* __restrict__ W1,
                         const void* __restrict__ W2,
                         void* __restrict__ out)
{
    __shared__ float lds[4][64 * LDSW];   // 20 KiB per block, per-wave slabs

    // ---- dtype sniff on `inputs` (proven in round 3): 128 even-indexed ushorts.
    // bf16 N(0,1): exponent field in [118,132] ~99%; fp32 low-mantissa halves ~6%.
    const int lane = threadIdx.x & 63;
    const ushort* xw = (const ushort*)x;
    const ushort a = xw[4 * lane];
    const ushort b = xw[4 * lane + 2];
    const int ea = (a >> 7) & 0xFF, eb = (b >> 7) & 0xFF;
    const int hit = ((ea >= 118 && ea <= 132) ? 1 : 0) + ((eb >= 118 && eb <= 132) ? 1 : 0);
    const unsigned long long m1 = __ballot(hit >= 1);
    const unsigned long long m2 = __ballot(hit >= 2);
    const int hits = __popcll(m1) + __popcll(m2);
    const bool is_bf16 = (hits >= 64);

    float* myLds = &lds[threadIdx.x >> 6][0];
    if (is_bf16) run_body<false>(x, W1, W2, out, myLds);
    else         run_body<true >(x, W1, W2, out, myLds);
}

extern "C" void kernel_launch(void* const* d_in, const int* in_sizes, int n_in,
                              void* d_out, int out_size, void* d_ws, size_t ws_size,
                              hipStream_t stream) {
    // Resolve inputs by element count (robust to the scalar t being dropped):
    //   inputs = 2097152, W1 = 262144, W2 = first 4096 (adjacency is the other 4096).
    int i_in = -1, i_w1 = -1, i_w2 = -1;
    for (int i = 0; i < n_in; ++i) {
        const int s = in_sizes[i];
        if      (s == BB * NN  && i_in < 0) i_in = i;
        else if (s == NN*HH*NN && i_w1 < 0) i_w1 = i;
        else if (s == NN*HH    && i_w2 < 0) i_w2 = i;
    }
    if (i_in < 0) i_in = (n_in > 1) ? 1 : 0;
    if (i_w1 < 0) i_w1 = i_in + 1;
    if (i_w2 < 0) i_w2 = i_w1 + 1;

    causal_deriv_kernel<<<dim3(16 * 128), dim3(256), 0, stream>>>(
        d_in[i_in], d_in[i_w1], d_in[i_w2], d_out);
}

// Round 7
// 118.014 us; speedup vs baseline: 1.7072x; 1.3234x over previous
//
#include <hip/hip_runtime.h>
#include <stdint.h>

// CausalDerivative: out[b,i] = sum_h W2[i,h] * relu(sum_n x[b,n]*W1[i,h,n]*M[i,n])
//   x[b,n] = (n<16) ? (inputs[b,n]>0 ? 1 : 0) : inputs[b,n]
//   M = ones, except row 63 keeps only n==63
// B=32768, N=64, H=64. Device tensors are FP32 (proven rounds 3/6); output fp32.
//
// Round 7:
//  - prep_kernel: gate+convert x, mask+convert W1 -> bf16 in d_ws ONCE
//    (removes the 16x-redundant f32->bf16 VALU work from the hot kernel)
//  - main_kernel: pure bf16 MFMA GEMM, NO barriers (per-wave LDS slab; DS pipe
//    is in-order per wave; round-4/5 NaN was dtype, not fencing), 3 blocks/CU
//  - fallback single kernel (round-6, proven) if ws_size is too small

typedef __attribute__((ext_vector_type(8))) short short8;   // 8 bf16
typedef __attribute__((ext_vector_type(4))) float floatx4;  // MFMA acc

#define NN 64
#define HH 64
#define BB 32768
#define ITER 4
#define LDSW 20   // LDS row stride in floats (80 B rows: 16B-aligned, 2-way-benign)
#define X_ELEMS (BB * NN)        // 2097152
#define W1_ELEMS (NN * HH * NN)  // 262144

__device__ __forceinline__ unsigned short f32_to_bf16_bits(float f) {
    union { float f; unsigned int i; } c; c.f = f;
    unsigned int b = c.i;
    b += 0x7fffu + ((b >> 16) & 1u);   // RNE
    return (unsigned short)(b >> 16);
}

__device__ __forceinline__ bool sniff_bf16(const void* x) {
    // bf16 N(0,1): exponent field in [118,132] ~99%; fp32 low-mantissa halves ~6%.
    const int lane = threadIdx.x & 63;
    const ushort* xw = (const ushort*)x;
    const ushort a = xw[4 * lane];
    const ushort b = xw[4 * lane + 2];
    const int ea = (a >> 7) & 0xFF, eb = (b >> 7) & 0xFF;
    const int hit = ((ea >= 118 && ea <= 132) ? 1 : 0) + ((eb >= 118 && eb <= 132) ? 1 : 0);
    const unsigned long long m1 = __ballot(hit >= 1);
    const unsigned long long m2 = __ballot(hit >= 2);
    return (__popcll(m1) + __popcll(m2)) >= 64;
}

// ---------------- prep: gate+convert x, mask+convert W1 into bf16 workspace ----
__global__ __launch_bounds__(256, 4)
void prep_kernel(const void* __restrict__ x, const void* __restrict__ w1,
                 ushort* __restrict__ xo, ushort* __restrict__ w1o)
{
    const bool is_bf16 = sniff_bf16(x);
    const long base = ((long)blockIdx.x * 256 + (long)threadIdx.x) * 8;

    if (base < X_ELEMS) {
        const bool gate = (base & 63) < 16;   // uniform: base%8==0, gate blocks of 8
        short8 v;
        if (is_bf16) {
            v = *(const short8*)((const ushort*)x + base);
            if (gate) {
                #pragma unroll
                for (int j = 0; j < 8; ++j) {
                    const unsigned short u = (unsigned short)v[j];
                    const bool pos = ((u & 0x8000u) == 0) && ((u & 0x7fffu) != 0);
                    v[j] = pos ? (short)0x3F80 : (short)0;
                }
            }
        } else {
            const float* p = (const float*)x + base;
            const float4 f0 = *(const float4*)(p);
            const float4 f1 = *(const float4*)(p + 4);
            const float vals[8] = {f0.x, f0.y, f0.z, f0.w, f1.x, f1.y, f1.z, f1.w};
            #pragma unroll
            for (int j = 0; j < 8; ++j) {
                if (gate) v[j] = (vals[j] > 0.f) ? (short)0x3F80 : (short)0;
                else      v[j] = (short)f32_to_bf16_bits(vals[j]);
            }
        }
        *(short8*)(xo + base) = v;
    } else {
        const long wb = base - X_ELEMS;
        if (wb < W1_ELEMS) {
            short8 v;
            if (is_bf16) {
                v = *(const short8*)((const ushort*)w1 + wb);
            } else {
                const float* p = (const float*)w1 + wb;
                const float4 f0 = *(const float4*)(p);
                const float4 f1 = *(const float4*)(p + 4);
                const float vals[8] = {f0.x, f0.y, f0.z, f0.w, f1.x, f1.y, f1.z, f1.w};
                #pragma unroll
                for (int j = 0; j < 8; ++j) v[j] = (short)f32_to_bf16_bits(vals[j]);
            }
            const int node = (int)(wb >> 12);        // 4096 elems per node
            if (node == NN - 1) {                    // hidden node: keep only n==63
                const int w63 = (int)(wb & 63);
                #pragma unroll
                for (int j = 0; j < 8; ++j)
                    if (w63 + j != NN - 1) v[j] = 0;
            }
            *(short8*)(w1o + wb) = v;
        }
    }
}

// ---------------- main: pure bf16 MFMA GEMM, barrier-free ---------------------
template<bool F32>
__device__ __forceinline__ void main_body(const ushort* __restrict__ xo,
                                          const ushort* __restrict__ w1o,
                                          const void* __restrict__ w2p,
                                          void* __restrict__ outp,
                                          float* myLds)
{
    const int tid  = threadIdx.x;
    const int wave = tid >> 6;
    const int lane = tid & 63;
    const int quad = lane >> 4;   // 0..3
    const int l16  = lane & 15;   // 0..15

    // blk = ng*128 + rbg : the 16 ng-blocks sharing an x row-chunk are 128 apart
    // (== 0 mod 8) -> same XCD L2 for the shared xo reads.
    const int blk  = blockIdx.x;
    const int ng   = blk >> 7;          // 0..15
    const int rbg  = blk & 127;         // 0..127
    const int node = ng * 4 + wave;     // 0..63
    const int rowbase = rbg * (ITER * 64);

    // ---- B fragments (loop-invariant): B[k][h] = W1[node][h][k]
    short8 bfrag[2][4];
    const ushort* w1n = w1o + node * (HH * NN);
    #pragma unroll
    for (int ks = 0; ks < 2; ++ks)
        #pragma unroll
        for (int ht = 0; ht < 4; ++ht)
            bfrag[ks][ht] = *(const short8*)(w1n + (ht * 16 + l16) * NN + ks * 32 + quad * 8);

    // ---- W2 (loop-invariant): lane (quad,l16) needs W2[node][ht*16+l16]
    float w2reg[4];
    #pragma unroll
    for (int ht = 0; ht < 4; ++ht) {
        const int idx = node * HH + ht * 16 + l16;
        if (F32) {
            w2reg[ht] = ((const float*)w2p)[idx];
        } else {
            const ushort u = ((const ushort*)w2p)[idx];
            union { unsigned int i; float f; } cv; cv.i = ((unsigned int)u) << 16;
            w2reg[ht] = cv.f;
        }
    }

    #pragma unroll 1
    for (int it = 0; it < ITER; ++it) {
        const int b0 = rowbase + it * 64;

        // ---- A fragments: A[m][k] = xo[b0+m][k]; m = rt*16+l16, k = ks*32+quad*8+j
        short8 afrag[2][4];
        #pragma unroll
        for (int ks = 0; ks < 2; ++ks)
            #pragma unroll
            for (int rt = 0; rt < 4; ++rt)
                afrag[ks][rt] = *(const short8*)(xo + (b0 + rt * 16 + l16) * NN + ks * 32 + quad * 8);

        // ---- MFMA: Hidden tile [64 rows x 64 h]
        floatx4 acc[4][4];
        #pragma unroll
        for (int rt = 0; rt < 4; ++rt)
            #pragma unroll
            for (int ht = 0; ht < 4; ++ht)
                acc[rt][ht] = (floatx4){0.f, 0.f, 0.f, 0.f};

        #pragma unroll
        for (int ks = 0; ks < 2; ++ks)
            #pragma unroll
            for (int rt = 0; rt < 4; ++rt)
                #pragma unroll
                for (int ht = 0; ht < 4; ++ht)
                    acc[rt][ht] = __builtin_amdgcn_mfma_f32_16x16x32_bf16(
                        afrag[ks][rt], bfrag[ks][ht], acc[rt][ht], 0, 0, 0);

        // ---- epilogue: per-lane partials over its 16 h-values -> per-wave LDS
        // transpose. Wave-private slab + in-order DS pipe => NO barrier needed.
        // C layout: col(h-offset)=l16, row=quad*4+r; lane holds h = ht*16+l16.
        #pragma unroll
        for (int rt = 0; rt < 4; ++rt) {
            #pragma unroll
            for (int r = 0; r < 4; ++r) {
                float s = 0.f;
                #pragma unroll
                for (int ht = 0; ht < 4; ++ht) {
                    float v = acc[rt][ht][r];
                    v = v > 0.f ? v : 0.f;
                    s = fmaf(v, w2reg[ht], s);
                }
                myLds[(rt * 16 + quad * 4 + r) * LDSW + l16] = s;
            }
        }

        // lane = local row: read its 16 partials (contiguous, 16B-aligned), reduce
        const float* rowp = myLds + lane * LDSW;
        const float4 v0 = *(const float4*)(rowp + 0);
        const float4 v1 = *(const float4*)(rowp + 4);
        const float4 v2 = *(const float4*)(rowp + 8);
        const float4 v3 = *(const float4*)(rowp + 12);
        const float s0 = (v0.x + v0.y) + (v0.z + v0.w);
        const float s1 = (v1.x + v1.y) + (v1.z + v1.w);
        const float s2 = (v2.x + v2.y) + (v2.z + v2.w);
        const float s3 = (v3.x + v3.y) + (v3.z + v3.w);
        const float tot = (s0 + s1) + (s2 + s3);

        if (F32) ((float*) outp)[(size_t)(b0 + lane) * NN + node] = tot;
        else     ((ushort*)outp)[(size_t)(b0 + lane) * NN + node] = f32_to_bf16_bits(tot);
    }
}

__global__ __launch_bounds__(256, 3)
void main_kernel(const void* __restrict__ xorig,
                 const ushort* __restrict__ xo, const ushort* __restrict__ w1o,
                 const void* __restrict__ w2p, void* __restrict__ outp)
{
    __shared__ float lds[4][64 * LDSW];   // 20 KiB/block, wave-private slabs
    const bool is_bf16 = sniff_bf16(xorig);   // out/W2 dtype follows input dtype
    float* myLds = &lds[threadIdx.x >> 6][0];
    if (is_bf16) main_body<false>(xo, w1o, w2p, outp, myLds);
    else         main_body<true >(xo, w1o, w2p, outp, myLds);
}

// ---------------- fallback: round-6 proven single kernel ----------------------
template<bool F32>
__device__ __forceinline__ void run_body_fb(const void* xp, const void* w1p,
                                            const void* w2p, void* outp,
                                            float* myLds)
{
    const int tid  = threadIdx.x;
    const int wave = tid >> 6;
    const int lane = tid & 63;
    const int quad = lane >> 4;
    const int l16  = lane & 15;
    const int blk  = blockIdx.x;
    const int ng   = blk >> 7;
    const int rbg  = blk & 127;
    const int node = ng * 4 + wave;
    const int rowbase = rbg * (ITER * 64);

    short8 bfrag[2][4];
    #pragma unroll
    for (int ks = 0; ks < 2; ++ks) {
        #pragma unroll
        for (int ht = 0; ht < 4; ++ht) {
            const int h = ht * 16 + l16;
            const int k = ks * 32 + quad * 8;
            short8 v;
            if (F32) {
                const float* p = (const float*)w1p + node * (HH * NN) + h * NN + k;
                const float4 a0 = *(const float4*)(p);
                const float4 a1 = *(const float4*)(p + 4);
                const float vals[8] = {a0.x, a0.y, a0.z, a0.w, a1.x, a1.y, a1.z, a1.w};
                #pragma unroll
                for (int j = 0; j < 8; ++j) v[j] = (short)f32_to_bf16_bits(vals[j]);
            } else {
                v = *(const short8*)((const ushort*)w1p + node * (HH * NN) + h * NN + k);
            }
            if (node == NN - 1) {
                #pragma unroll
                for (int j = 0; j < 8; ++j)
                    if (k + j != NN - 1) v[j] = 0;
            }
            bfrag[ks][ht] = v;
        }
    }

    float w2reg[4];
    #pragma unroll
    for (int ht = 0; ht < 4; ++ht) {
        const int idx = node * HH + ht * 16 + l16;
        if (F32) {
            w2reg[ht] = ((const float*)w2p)[idx];
        } else {
            const ushort u = ((const ushort*)w2p)[idx];
            union { unsigned int i; float f; } cv; cv.i = ((unsigned int)u) << 16;
            w2reg[ht] = cv.f;
        }
    }

    #pragma unroll 1
    for (int it = 0; it < ITER; ++it) {
        const int b0 = rowbase + it * 64;
        short8 afrag[2][4];
        #pragma unroll
        for (int ks = 0; ks < 2; ++ks) {
            #pragma unroll
            for (int rt = 0; rt < 4; ++rt) {
                const int row = b0 + rt * 16 + l16;
                const int k   = ks * 32 + quad * 8;
                const bool gate = (ks == 0 && quad < 2);
                short8 v;
                if (F32) {
                    const float* p = (const float*)xp + row * NN + k;
                    const float4 a0 = *(const float4*)(p);
                    const float4 a1 = *(const float4*)(p + 4);
                    const float vals[8] = {a0.x, a0.y, a0.z, a0.w, a1.x, a1.y, a1.z, a1.w};
                    #pragma unroll
                    for (int j = 0; j < 8; ++j) {
                        if (gate) v[j] = (vals[j] > 0.f) ? (short)0x3F80 : (short)0;
                        else      v[j] = (short)f32_to_bf16_bits(vals[j]);
                    }
                } else {
                    v = *(const short8*)((const ushort*)xp + row * NN + k);
                    if (gate) {
                        #pragma unroll
                        for (int j = 0; j < 8; ++j) {
                            const unsigned short u = (unsigned short)v[j];
                            const bool pos = ((u & 0x8000u) == 0) && ((u & 0x7fffu) != 0);
                            v[j] = pos ? (short)0x3F80 : (short)0;
                        }
                    }
                }
                afrag[ks][rt] = v;
            }
        }

        floatx4 acc[4][4];
        #pragma unroll
        for (int rt = 0; rt < 4; ++rt)
            #pragma unroll
            for (int ht = 0; ht < 4; ++ht)
                acc[rt][ht] = (floatx4){0.f, 0.f, 0.f, 0.f};
        #pragma unroll
        for (int ks = 0; ks < 2; ++ks)
            #pragma unroll
            for (int rt = 0; rt < 4; ++rt)
                #pragma unroll
                for (int ht = 0; ht < 4; ++ht)
                    acc[rt][ht] = __builtin_amdgcn_mfma_f32_16x16x32_bf16(
                        afrag[ks][rt], bfrag[ks][ht], acc[rt][ht], 0, 0, 0);

        #pragma unroll
        for (int rt = 0; rt < 4; ++rt) {
            #pragma unroll
            for (int r = 0; r < 4; ++r) {
                float s = 0.f;
                #pragma unroll
                for (int ht = 0; ht < 4; ++ht) {
                    float v = acc[rt][ht][r];
                    v = v > 0.f ? v : 0.f;
                    s = fmaf(v, w2reg[ht], s);
                }
                myLds[(rt * 16 + quad * 4 + r) * LDSW + l16] = s;
            }
        }
        __syncthreads();
        const float* rowp = myLds + lane * LDSW;
        const float4 v0 = *(const float4*)(rowp + 0);
        const float4 v1 = *(const float4*)(rowp + 4);
        const float4 v2 = *(const float4*)(rowp + 8);
        const float4 v3 = *(const float4*)(rowp + 12);
        const float tot = (((v0.x + v0.y) + (v0.z + v0.w)) + ((v1.x + v1.y) + (v1.z + v1.w)))
                        + (((v2.x + v2.y) + (v2.z + v2.w)) + ((v3.x + v3.y) + (v3.z + v3.w)));
        if (F32) ((float*) outp)[(size_t)(b0 + lane) * NN + node] = tot;
        else     ((ushort*)outp)[(size_t)(b0 + lane) * NN + node] = f32_to_bf16_bits(tot);
        __syncthreads();
    }
}

__global__ __launch_bounds__(256, 2)
void fallback_kernel(const void* __restrict__ x, const void* __restrict__ W1,
                     const void* __restrict__ W2, void* __restrict__ out)
{
    __shared__ float lds[4][64 * LDSW];
    const bool is_bf16 = sniff_bf16(x);
    float* myLds = &lds[threadIdx.x >> 6][0];
    if (is_bf16) run_body_fb<false>(x, W1, W2, out, myLds);
    else         run_body_fb<true >(x, W1, W2, out, myLds);
}

extern "C" void kernel_launch(void* const* d_in, const int* in_sizes, int n_in,
                              void* d_out, int out_size, void* d_ws, size_t ws_size,
                              hipStream_t stream) {
    // Resolve inputs by element count (robust to the scalar t being dropped):
    //   inputs = 2097152, W1 = 262144, W2 = first 4096 (adjacency is the other 4096).
    int i_in = -1, i_w1 = -1, i_w2 = -1;
    for (int i = 0; i < n_in; ++i) {
        const int s = in_sizes[i];
        if      (s == BB * NN  && i_in < 0) i_in = i;
        else if (s == NN*HH*NN && i_w1 < 0) i_w1 = i;
        else if (s == NN*HH    && i_w2 < 0) i_w2 = i;
    }
    if (i_in < 0) i_in = (n_in > 1) ? 1 : 0;
    if (i_w1 < 0) i_w1 = i_in + 1;
    if (i_w2 < 0) i_w2 = i_w1 + 1;

    const size_t need = (size_t)(X_ELEMS + W1_ELEMS) * sizeof(ushort);  // 4.5 MiB
    if (ws_size >= need) {
        ushort* xo  = (ushort*)d_ws;
        ushort* w1o = xo + X_ELEMS;
        prep_kernel<<<dim3((X_ELEMS + W1_ELEMS) / (256 * 8)), dim3(256), 0, stream>>>(
            d_in[i_in], d_in[i_w1], xo, w1o);
        main_kernel<<<dim3(16 * 128), dim3(256), 0, stream>>>(
            d_in[i_in], xo, w1o, d_in[i_w2], d_out);
    } else {
        fallback_kernel<<<dim3(16 * 128), dim3(256), 0, stream>>>(
            d_in[i_in], d_in[i_w1], d_in[i_w2], d_out);
    }
}

// Round 8
// 116.239 us; speedup vs baseline: 1.7333x; 1.0153x over previous
//
#include <hip/hip_runtime.h>
#include <stdint.h>

// CausalDerivative: out[b,i] = sum_h W2[i,h] * relu(sum_n x[b,n]*W1[i,h,n]*M[i,n])
//   x[b,n] = (n<16) ? (inputs[b,n]>0 ? 1 : 0) : inputs[b,n]
//   M = ones, except row 63 keeps only n==63
// B=32768, N=64, H=64. Device tensors FP32 (proven r3/6/7); dual-path kept.
//
// Round 8: kill the 3.5x write amplification (r7: WRITE_SIZE 29 MB vs 8.4 MB
// ideal). Block = 16 consecutive nodes x 64 rows; wave = 4 nodes; A-frags
// loaded once per wave (4x reuse); B-frags prefetched one node ahead; per-node
// wave-private LDS-slab epilogue (proven, barrier-free); results staged in an
// LDS out-tile and written as full-cache-line coalesced float4 bursts.

typedef __attribute__((ext_vector_type(8))) short short8;   // 8 bf16
typedef __attribute__((ext_vector_type(4))) float floatx4;  // MFMA acc

#define NN 64
#define HH 64
#define BB 32768
#define LDSW 20   // slab/out-tile row stride in floats (80 B, 16B-aligned rows)
#define X_ELEMS (BB * NN)        // 2097152
#define W1_ELEMS (NN * HH * NN)  // 262144

__device__ __forceinline__ unsigned short f32_to_bf16_bits(float f) {
    union { float f; unsigned int i; } c; c.f = f;
    unsigned int b = c.i;
    b += 0x7fffu + ((b >> 16) & 1u);   // RNE
    return (unsigned short)(b >> 16);
}

__device__ __forceinline__ bool sniff_bf16(const void* x) {
    // bf16 N(0,1): exponent field in [118,132] ~99%; fp32 low-mantissa halves ~6%.
    const int lane = threadIdx.x & 63;
    const ushort* xw = (const ushort*)x;
    const ushort a = xw[4 * lane];
    const ushort b = xw[4 * lane + 2];
    const int ea = (a >> 7) & 0xFF, eb = (b >> 7) & 0xFF;
    const int hit = ((ea >= 118 && ea <= 132) ? 1 : 0) + ((eb >= 118 && eb <= 132) ? 1 : 0);
    const unsigned long long m1 = __ballot(hit >= 1);
    const unsigned long long m2 = __ballot(hit >= 2);
    return (__popcll(m1) + __popcll(m2)) >= 64;
}

// ---------------- prep: gate+convert x, mask+convert W1 into bf16 workspace ----
__global__ __launch_bounds__(256, 4)
void prep_kernel(const void* __restrict__ x, const void* __restrict__ w1,
                 ushort* __restrict__ xo, ushort* __restrict__ w1o)
{
    const bool is_bf16 = sniff_bf16(x);
    const long base = ((long)blockIdx.x * 256 + (long)threadIdx.x) * 8;

    if (base < X_ELEMS) {
        const bool gate = (base & 63) < 16;   // uniform per 8-elem chunk
        short8 v;
        if (is_bf16) {
            v = *(const short8*)((const ushort*)x + base);
            if (gate) {
                #pragma unroll
                for (int j = 0; j < 8; ++j) {
                    const unsigned short u = (unsigned short)v[j];
                    const bool pos = ((u & 0x8000u) == 0) && ((u & 0x7fffu) != 0);
                    v[j] = pos ? (short)0x3F80 : (short)0;
                }
            }
        } else {
            const float* p = (const float*)x + base;
            const float4 f0 = *(const float4*)(p);
            const float4 f1 = *(const float4*)(p + 4);
            const float vals[8] = {f0.x, f0.y, f0.z, f0.w, f1.x, f1.y, f1.z, f1.w};
            #pragma unroll
            for (int j = 0; j < 8; ++j) {
                if (gate) v[j] = (vals[j] > 0.f) ? (short)0x3F80 : (short)0;
                else      v[j] = (short)f32_to_bf16_bits(vals[j]);
            }
        }
        *(short8*)(xo + base) = v;
    } else {
        const long wb = base - X_ELEMS;
        if (wb < W1_ELEMS) {
            short8 v;
            if (is_bf16) {
                v = *(const short8*)((const ushort*)w1 + wb);
            } else {
                const float* p = (const float*)w1 + wb;
                const float4 f0 = *(const float4*)(p);
                const float4 f1 = *(const float4*)(p + 4);
                const float vals[8] = {f0.x, f0.y, f0.z, f0.w, f1.x, f1.y, f1.z, f1.w};
                #pragma unroll
                for (int j = 0; j < 8; ++j) v[j] = (short)f32_to_bf16_bits(vals[j]);
            }
            const int node = (int)(wb >> 12);        // 4096 elems per node
            if (node == NN - 1) {                    // hidden node: keep only n==63
                const int w63 = (int)(wb & 63);
                #pragma unroll
                for (int j = 0; j < 8; ++j)
                    if (w63 + j != NN - 1) v[j] = 0;
            }
            *(short8*)(w1o + wb) = v;
        }
    }
}

// ---------------- main: bf16 MFMA GEMM, coalesced full-line output ------------
template<bool F32>
__device__ __forceinline__ void main_body(const ushort* __restrict__ xo,
                                          const ushort* __restrict__ w1o,
                                          const void* __restrict__ w2p,
                                          void* __restrict__ outp,
                                          float* slab, float* outTile)
{
    const int tid  = threadIdx.x;
    const int wave = tid >> 6;
    const int lane = tid & 63;
    const int quad = lane >> 4;   // 0..3
    const int l16  = lane & 15;   // 0..15

    // blk = ng*512 + rbg : the 4 ng-blocks sharing an x row-chunk are 512 apart
    // (== 0 mod 8) -> same XCD L2 for the shared xo reads.
    const int blk  = blockIdx.x;
    const int ng   = blk >> 9;          // 0..3   (16-node group)
    const int rbg  = blk & 511;         // 0..511 (64-row chunk)
    const int b0   = rbg * 64;
    const int nbase = ng * 16 + wave * 4;   // this wave's 4 nodes

    // ---- A fragments, loaded ONCE (reused by 4 node-GEMMs):
    //      A[m][k] = xo[b0+m][k]; m = rt*16+l16, k = ks*32+quad*8+j
    short8 afrag[2][4];
    #pragma unroll
    for (int ks = 0; ks < 2; ++ks)
        #pragma unroll
        for (int rt = 0; rt < 4; ++rt)
            afrag[ks][rt] = *(const short8*)(xo + (b0 + rt * 16 + l16) * NN + ks * 32 + quad * 8);

    // ---- W2 for the 4 nodes upfront: lane (quad,l16) needs W2[node][ht*16+l16]
    float w2reg[4][4];
    #pragma unroll
    for (int nl = 0; nl < 4; ++nl) {
        #pragma unroll
        for (int ht = 0; ht < 4; ++ht) {
            const int idx = (nbase + nl) * HH + ht * 16 + l16;
            if (F32) {
                w2reg[nl][ht] = ((const float*)w2p)[idx];
            } else {
                const ushort u = ((const ushort*)w2p)[idx];
                union { unsigned int i; float f; } cv; cv.i = ((unsigned int)u) << 16;
                w2reg[nl][ht] = cv.f;
            }
        }
    }

    // ---- B fragments for node 0, then prefetch one node ahead in the loop
    //      B[k][h] = W1[node][h][k]; h = ht*16+l16, k = ks*32+quad*8+j
    short8 bcur[2][4], bnxt[2][4];
    {
        const ushort* w1n = w1o + nbase * (HH * NN);
        #pragma unroll
        for (int ks = 0; ks < 2; ++ks)
            #pragma unroll
            for (int ht = 0; ht < 4; ++ht)
                bcur[ks][ht] = *(const short8*)(w1n + (ht * 16 + l16) * NN + ks * 32 + quad * 8);
    }

    #pragma unroll 1
    for (int nl = 0; nl < 4; ++nl) {
        if (nl < 3) {
            const ushort* w1n = w1o + (nbase + nl + 1) * (HH * NN);
            #pragma unroll
            for (int ks = 0; ks < 2; ++ks)
                #pragma unroll
                for (int ht = 0; ht < 4; ++ht)
                    bnxt[ks][ht] = *(const short8*)(w1n + (ht * 16 + l16) * NN + ks * 32 + quad * 8);
        }

        // ---- MFMA: Hidden tile [64 rows x 64 h] for node nbase+nl
        floatx4 acc[4][4];
        #pragma unroll
        for (int rt = 0; rt < 4; ++rt)
            #pragma unroll
            for (int ht = 0; ht < 4; ++ht)
                acc[rt][ht] = (floatx4){0.f, 0.f, 0.f, 0.f};

        #pragma unroll
        for (int ks = 0; ks < 2; ++ks)
            #pragma unroll
            for (int rt = 0; rt < 4; ++rt)
                #pragma unroll
                for (int ht = 0; ht < 4; ++ht)
                    acc[rt][ht] = __builtin_amdgcn_mfma_f32_16x16x32_bf16(
                        afrag[ks][rt], bcur[ks][ht], acc[rt][ht], 0, 0, 0);

        // ---- per-node epilogue: relu*W2 partials -> wave-private slab transpose
        // C layout: col(h-offset)=l16, row=quad*4+r; lane holds h = ht*16+l16.
        // Wave-private slab + in-order DS pipe => no barrier (proven r7).
        #pragma unroll
        for (int rt = 0; rt < 4; ++rt) {
            #pragma unroll
            for (int r = 0; r < 4; ++r) {
                float s = 0.f;
                #pragma unroll
                for (int ht = 0; ht < 4; ++ht) {
                    float v = acc[rt][ht][r];
                    v = v > 0.f ? v : 0.f;
                    s = fmaf(v, w2reg[nl][ht], s);
                }
                slab[(rt * 16 + quad * 4 + r) * LDSW + l16] = s;
            }
        }

        // lane = local row: reduce its 16 partials (contiguous, 16B-aligned)
        const float* rowp = slab + lane * LDSW;
        const float4 v0 = *(const float4*)(rowp + 0);
        const float4 v1 = *(const float4*)(rowp + 4);
        const float4 v2 = *(const float4*)(rowp + 8);
        const float4 v3 = *(const float4*)(rowp + 12);
        const float tot = (((v0.x + v0.y) + (v0.z + v0.w)) + ((v1.x + v1.y) + (v1.z + v1.w)))
                        + (((v2.x + v2.y) + (v2.z + v2.w)) + ((v3.x + v3.y) + (v3.z + v3.w)));

        // stage into block out-tile: row = lane, col = wave*4+nl (disjoint per wave)
        outTile[lane * LDSW + wave * 4 + nl] = tot;

        if (nl < 3) {
            #pragma unroll
            for (int ks = 0; ks < 2; ++ks)
                #pragma unroll
                for (int ht = 0; ht < 4; ++ht)
                    bcur[ks][ht] = bnxt[ks][ht];
        }
    }

    __syncthreads();   // all 16 out-tile columns written

    // ---- coalesced output: thread -> (row = tid>>2, c = tid&3), 16B each;
    // 4 consecutive threads fully cover each 64B line of out.
    const int row = tid >> 2;
    const int c   = tid & 3;
    const float4 v = *(const float4*)(outTile + row * LDSW + c * 4);
    const size_t obase = (size_t)(b0 + row) * NN + ng * 16 + c * 4;
    if (F32) {
        *(float4*)((float*)outp + obase) = v;
    } else {
        ushort4 o;
        o.x = f32_to_bf16_bits(v.x); o.y = f32_to_bf16_bits(v.y);
        o.z = f32_to_bf16_bits(v.z); o.w = f32_to_bf16_bits(v.w);
        *(ushort4*)((ushort*)outp + obase) = o;
    }
}

__global__ __launch_bounds__(256, 2)
void main_kernel(const void* __restrict__ xorig,
                 const ushort* __restrict__ xo, const ushort* __restrict__ w1o,
                 const void* __restrict__ w2p, void* __restrict__ outp)
{
    __shared__ float lds[5 * 64 * LDSW];   // 4 wave slabs + out-tile = 25.6 KB
    const bool is_bf16 = sniff_bf16(xorig);
    float* slab    = &lds[(threadIdx.x >> 6) * 64 * LDSW];
    float* outTile = &lds[4 * 64 * LDSW];
    if (is_bf16) main_body<false>(xo, w1o, w2p, outp, slab, outTile);
    else         main_body<true >(xo, w1o, w2p, outp, slab, outTile);
}

// ---------------- fallback: round-6 proven single kernel ----------------------
template<bool F32>
__device__ __forceinline__ void run_body_fb(const void* xp, const void* w1p,
                                            const void* w2p, void* outp,
                                            float* myLds)
{
    const int tid  = threadIdx.x;
    const int wave = tid >> 6;
    const int lane = tid & 63;
    const int quad = lane >> 4;
    const int l16  = lane & 15;
    const int blk  = blockIdx.x;
    const int ng   = blk >> 7;
    const int rbg  = blk & 127;
    const int node = ng * 4 + wave;
    const int rowbase = rbg * 256;

    short8 bfrag[2][4];
    #pragma unroll
    for (int ks = 0; ks < 2; ++ks) {
        #pragma unroll
        for (int ht = 0; ht < 4; ++ht) {
            const int h = ht * 16 + l16;
            const int k = ks * 32 + quad * 8;
            short8 v;
            if (F32) {
                const float* p = (const float*)w1p + node * (HH * NN) + h * NN + k;
                const float4 a0 = *(const float4*)(p);
                const float4 a1 = *(const float4*)(p + 4);
                const float vals[8] = {a0.x, a0.y, a0.z, a0.w, a1.x, a1.y, a1.z, a1.w};
                #pragma unroll
                for (int j = 0; j < 8; ++j) v[j] = (short)f32_to_bf16_bits(vals[j]);
            } else {
                v = *(const short8*)((const ushort*)w1p + node * (HH * NN) + h * NN + k);
            }
            if (node == NN - 1) {
                #pragma unroll
                for (int j = 0; j < 8; ++j)
                    if (k + j != NN - 1) v[j] = 0;
            }
            bfrag[ks][ht] = v;
        }
    }

    float w2reg[4];
    #pragma unroll
    for (int ht = 0; ht < 4; ++ht) {
        const int idx = node * HH + ht * 16 + l16;
        if (F32) {
            w2reg[ht] = ((const float*)w2p)[idx];
        } else {
            const ushort u = ((const ushort*)w2p)[idx];
            union { unsigned int i; float f; } cv; cv.i = ((unsigned int)u) << 16;
            w2reg[ht] = cv.f;
        }
    }

    #pragma unroll 1
    for (int it = 0; it < 4; ++it) {
        const int b0 = rowbase + it * 64;
        short8 afrag[2][4];
        #pragma unroll
        for (int ks = 0; ks < 2; ++ks) {
            #pragma unroll
            for (int rt = 0; rt < 4; ++rt) {
                const int rowg = b0 + rt * 16 + l16;
                const int k    = ks * 32 + quad * 8;
                const bool gate = (ks == 0 && quad < 2);
                short8 v;
                if (F32) {
                    const float* p = (const float*)xp + rowg * NN + k;
                    const float4 a0 = *(const float4*)(p);
                    const float4 a1 = *(const float4*)(p + 4);
                    const float vals[8] = {a0.x, a0.y, a0.z, a0.w, a1.x, a1.y, a1.z, a1.w};
                    #pragma unroll
                    for (int j = 0; j < 8; ++j) {
                        if (gate) v[j] = (vals[j] > 0.f) ? (short)0x3F80 : (short)0;
                        else      v[j] = (short)f32_to_bf16_bits(vals[j]);
                    }
                } else {
                    v = *(const short8*)((const ushort*)xp + rowg * NN + k);
                    if (gate) {
                        #pragma unroll
                        for (int j = 0; j < 8; ++j) {
                            const unsigned short u = (unsigned short)v[j];
                            const bool pos = ((u & 0x8000u) == 0) && ((u & 0x7fffu) != 0);
                            v[j] = pos ? (short)0x3F80 : (short)0;
                        }
                    }
                }
                afrag[ks][rt] = v;
            }
        }

        floatx4 acc[4][4];
        #pragma unroll
        for (int rt = 0; rt < 4; ++rt)
            #pragma unroll
            for (int ht = 0; ht < 4; ++ht)
                acc[rt][ht] = (floatx4){0.f, 0.f, 0.f, 0.f};
        #pragma unroll
        for (int ks = 0; ks < 2; ++ks)
            #pragma unroll
            for (int rt = 0; rt < 4; ++rt)
                #pragma unroll
                for (int ht = 0; ht < 4; ++ht)
                    acc[rt][ht] = __builtin_amdgcn_mfma_f32_16x16x32_bf16(
                        afrag[ks][rt], bfrag[ks][ht], acc[rt][ht], 0, 0, 0);

        #pragma unroll
        for (int rt = 0; rt < 4; ++rt) {
            #pragma unroll
            for (int r = 0; r < 4; ++r) {
                float s = 0.f;
                #pragma unroll
                for (int ht = 0; ht < 4; ++ht) {
                    float v = acc[rt][ht][r];
                    v = v > 0.f ? v : 0.f;
                    s = fmaf(v, w2reg[ht], s);
                }
                myLds[(rt * 16 + quad * 4 + r) * LDSW + l16] = s;
            }
        }
        __syncthreads();
        const float* rowp = myLds + lane * LDSW;
        const float4 v0 = *(const float4*)(rowp + 0);
        const float4 v1 = *(const float4*)(rowp + 4);
        const float4 v2 = *(const float4*)(rowp + 8);
        const float4 v3 = *(const float4*)(rowp + 12);
        const float tot = (((v0.x + v0.y) + (v0.z + v0.w)) + ((v1.x + v1.y) + (v1.z + v1.w)))
                        + (((v2.x + v2.y) + (v2.z + v2.w)) + ((v3.x + v3.y) + (v3.z + v3.w)));
        if (F32) ((float*) outp)[(size_t)(b0 + lane) * NN + node] = tot;
        else     ((ushort*)outp)[(size_t)(b0 + lane) * NN + node] = f32_to_bf16_bits(tot);
        __syncthreads();
    }
}

__global__ __launch_bounds__(256, 2)
void fallback_kernel(const void* __restrict__ x, const void* __restrict__ W1,
                     const void* __restrict__ W2, void* __restrict__ out)
{
    __shared__ float lds[4][64 * LDSW];
    const bool is_bf16 = sniff_bf16(x);
    float* myLds = &lds[threadIdx.x >> 6][0];
    if (is_bf16) run_body_fb<false>(x, W1, W2, out, myLds);
    else         run_body_fb<true >(x, W1, W2, out, myLds);
}

extern "C" void kernel_launch(void* const* d_in, const int* in_sizes, int n_in,
                              void* d_out, int out_size, void* d_ws, size_t ws_size,
                              hipStream_t stream) {
    // Resolve inputs by element count (robust to the scalar t being dropped):
    //   inputs = 2097152, W1 = 262144, W2 = first 4096 (adjacency is the other 4096).
    int i_in = -1, i_w1 = -1, i_w2 = -1;
    for (int i = 0; i < n_in; ++i) {
        const int s = in_sizes[i];
        if      (s == BB * NN  && i_in < 0) i_in = i;
        else if (s == NN*HH*NN && i_w1 < 0) i_w1 = i;
        else if (s == NN*HH    && i_w2 < 0) i_w2 = i;
    }
    if (i_in < 0) i_in = (n_in > 1) ? 1 : 0;
    if (i_w1 < 0) i_w1 = i_in + 1;
    if (i_w2 < 0) i_w2 = i_w1 + 1;

    const size_t need = (size_t)(X_ELEMS + W1_ELEMS) * sizeof(ushort);  // 4.5 MiB
    if (ws_size >= need) {
        ushort* xo  = (ushort*)d_ws;
        ushort* w1o = xo + X_ELEMS;
        prep_kernel<<<dim3((X_ELEMS + W1_ELEMS) / (256 * 8)), dim3(256), 0, stream>>>(
            d_in[i_in], d_in[i_w1], xo, w1o);
        main_kernel<<<dim3(4 * 512), dim3(256), 0, stream>>>(
            d_in[i_in], xo, w1o, d_in[i_w2], d_out);
    } else {
        fallback_kernel<<<dim3(16 * 128), dim3(256), 0, stream>>>(
            d_in[i_in], d_in[i_w1], d_in[i_w2], d_out);
    }
}